// Round 4
// baseline (845.012 us; speedup 1.0000x reference)
//
#include <hip/hip_runtime.h>
#include <hip/hip_bf16.h>
#include <math.h>

// ---------------- problem constants ----------------
#define B_SZ   2
#define L_SZ   2048
#define DM     1024          // d_model
#define DI     2048          // d_inner
#define DS     16            // d_state
#define DC     4             // d_conv
#define M_SZ   (B_SZ * L_SZ) // 4096 rows
#define N_XZ   (2 * DI)      // 4096
// ws layout (floats):
//   xz : [0,        16777216)   M_SZ*N_XZ
//   xc : [16777216, 25165824)   M_SZ*DI   (conv+silu out; later aliased by y_gated)
//   Bm : [25165824, 25231360)   M_SZ*DS
//   Cm : [25231360, 25296896)   M_SZ*DS

typedef short bf16x8 __attribute__((ext_vector_type(8)));
typedef float f32x4  __attribute__((ext_vector_type(4)));

// pack two fp32 -> two bf16 (RNE) in one dword (a=lo, b=hi)
__device__ __forceinline__ unsigned int pk_bf16(float a, float b) {
  unsigned int ua = __builtin_bit_cast(unsigned int, a);
  unsigned int ub = __builtin_bit_cast(unsigned int, b);
  ua += 0x7FFFu + ((ua >> 16) & 1u);
  ub += 0x7FFFu + ((ub >> 16) & 1u);
  return (ua >> 16) | (ub & 0xFFFF0000u);
}

// ---------------- fp32 GEMM for xi half only (feeds the scan -> fp32) ----------------
// xz[:, 0:2048] = x @ W_in[:, 0:2048] + b_in[0:2048]
// 128x128 tile, BK=16, 256 threads, 8x8/thread split 4+4 rows/cols at +64
// (fragment reads stride-4 -> 2-way bank alias max = free).
__global__ __launch_bounds__(256, 2) void gemm_xi_f32(
    const float* __restrict__ A,    // x (M_SZ x DM)
    const float* __restrict__ B,    // W_in (DM x N_XZ), using cols 0..2047
    const float* __restrict__ bias, float* __restrict__ C) {  // xz, stride N_XZ
  __shared__ float As[16][132];   // transposed A tile, +4 pad
  __shared__ float Bs[16][128];
  const int tid = threadIdx.x;
  const int tr = tid >> 4;        // 0..15
  const int tc = tid & 15;        // 0..15
  const int row0 = blockIdx.y * 128, col0 = blockIdx.x * 128;

  float acc[8][8] = {};   // [ii*4+i][jj*4+j] -> row +ii*64+tr*4+i, col +jj*64+tc*4+j

  for (int k0 = 0; k0 < DM; k0 += 16) {
    __syncthreads();
    // A tile: 128 rows x 16 k; 2 float4/thread along k, stored transposed (2-way store alias)
    #pragma unroll
    for (int i = 0; i < 2; ++i) {
      int idx = tid + i * 256, r = idx >> 2, q = idx & 3;
      float4 v = *(const float4*)(A + (size_t)(row0 + r) * DM + k0 + q * 4);
      As[q * 4 + 0][r] = v.x; As[q * 4 + 1][r] = v.y;
      As[q * 4 + 2][r] = v.z; As[q * 4 + 3][r] = v.w;
    }
    // B tile: 16 k x 128 n, coalesced float4
    #pragma unroll
    for (int i = 0; i < 2; ++i) {
      int idx = tid + i * 256, kk = idx >> 5, qc = idx & 31;
      *(float4*)&Bs[kk][qc * 4] =
          *(const float4*)(B + (size_t)(k0 + kk) * N_XZ + col0 + qc * 4);
    }
    __syncthreads();
    #pragma unroll
    for (int kk = 0; kk < 16; ++kk) {
      float a[8], b[8];
      *(float4*)&a[0] = *(const float4*)&As[kk][tr * 4];        // 4 bcast addrs, banks 0/4/8/12
      *(float4*)&a[4] = *(const float4*)&As[kk][64 + tr * 4];
      *(float4*)&b[0] = *(const float4*)&Bs[kk][tc * 4];        // stride-4: 2-way = free
      *(float4*)&b[4] = *(const float4*)&Bs[kk][64 + tc * 4];
      #pragma unroll
      for (int i2 = 0; i2 < 8; ++i2)
        #pragma unroll
        for (int j2 = 0; j2 < 8; ++j2)
          acc[i2][j2] = fmaf(a[i2], b[j2], acc[i2][j2]);
    }
  }
  #pragma unroll
  for (int ii = 0; ii < 2; ++ii)
    #pragma unroll
    for (int i = 0; i < 4; ++i) {
      int r = row0 + ii * 64 + tr * 4 + i;
      #pragma unroll
      for (int jj = 0; jj < 2; ++jj) {
        int c = col0 + jj * 64 + tc * 4;
        float4 o;
        o.x = acc[ii * 4 + i][jj * 4 + 0] + bias[c + 0];
        o.y = acc[ii * 4 + i][jj * 4 + 1] + bias[c + 1];
        o.z = acc[ii * 4 + i][jj * 4 + 2] + bias[c + 2];
        o.w = acc[ii * 4 + i][jj * 4 + 3] + bias[c + 3];
        *(float4*)(C + (size_t)r * N_XZ + c) = o;
      }
    }
}

// ---------------- bf16 MFMA GEMM, generalized strides ----------------
// C[M x N] = A[M x K] @ B[K x N] + bias ; used for z-half of GEMM1 and GEMM2.
// 128x128 tile, BK=32, 256 thr = 4 waves (2x2), each wave 4x4 16x16x32 frags.
// fp32 inputs converted to bf16 (RNE) in-register during LDS staging.
#define LDF 20   // uints per LDS row (32 bf16 data + 8 pad)
__global__ __launch_bounds__(256, 3) void gemm_mfma(
    const float* __restrict__ A, int lda,
    const float* __restrict__ B, int ldb,    // pre-offset to col region
    const float* __restrict__ bias, float* __restrict__ C, int ldc, int K) {
  __shared__ unsigned int As[128 * LDF];  // [row][k] bf16 pairs
  __shared__ unsigned int Bs[128 * LDF];  // [col][k] bf16 pairs (transposed)
  const int tid  = threadIdx.x;
  const int lane = tid & 63, wave = tid >> 6;
  const int wr = wave >> 1, wc = wave & 1;
  const int lm = lane & 15, lq = lane >> 4;
  const int row0 = blockIdx.y * 128, col0 = blockIdx.x * 128;

  f32x4 acc[4][4];
  #pragma unroll
  for (int i = 0; i < 4; ++i)
    #pragma unroll
    for (int j = 0; j < 4; ++j) acc[i][j] = (f32x4){0.f, 0.f, 0.f, 0.f};

  for (int k0 = 0; k0 < K; k0 += 32) {
    __syncthreads();
    // A: 128 rows x 32 k; float4 along k -> bf16x4 (8B) store
    #pragma unroll
    for (int i = 0; i < 4; ++i) {
      int idx = tid + i * 256, r = idx >> 3, q = idx & 7;
      float4 v = *(const float4*)(A + (size_t)(row0 + r) * lda + k0 + q * 4);
      *(uint2*)&As[r * LDF + q * 2] =
          make_uint2(pk_bf16(v.x, v.y), pk_bf16(v.z, v.w));
    }
    // B: 32 k x 128 n -> [n][k]; gather 4 k's per n (coalesced over n)
    #pragma unroll
    for (int i = 0; i < 4; ++i) {
      int idx = tid + i * 256, n = idx & 127, kq = idx >> 7;
      const float* bp = B + (size_t)(k0 + kq * 4) * ldb + col0 + n;
      float b0 = bp[0], b1 = bp[ldb], b2 = bp[2 * ldb], b3 = bp[3 * ldb];
      *(uint2*)&Bs[n * LDF + kq * 2] =
          make_uint2(pk_bf16(b0, b1), pk_bf16(b2, b3));
    }
    __syncthreads();
    bf16x8 af[4], bf[4];
    #pragma unroll
    for (int i = 0; i < 4; ++i)
      af[i] = *(const bf16x8*)&As[(wr * 64 + i * 16 + lm) * LDF + lq * 4];
    #pragma unroll
    for (int j = 0; j < 4; ++j)
      bf[j] = *(const bf16x8*)&Bs[(wc * 64 + j * 16 + lm) * LDF + lq * 4];
    #pragma unroll
    for (int i = 0; i < 4; ++i)
      #pragma unroll
      for (int j = 0; j < 4; ++j)
        acc[i][j] = __builtin_amdgcn_mfma_f32_16x16x32_bf16(af[i], bf[j], acc[i][j], 0, 0, 0);
  }
  // epilogue: C/D layout col=lane&15, row=(lane>>4)*4+reg
  #pragma unroll
  for (int i = 0; i < 4; ++i) {
    int r = row0 + wr * 64 + i * 16 + lq * 4;
    #pragma unroll
    for (int j = 0; j < 4; ++j) {
      int c = col0 + wc * 64 + j * 16 + lm;
      float bs = bias[c];
      #pragma unroll
      for (int k = 0; k < 4; ++k)
        C[(size_t)(r + k) * ldc + c] = acc[i][j][k] + bs;
    }
  }
}

// ---------------- depthwise causal conv (k=4, left pad 3) + SiLU ----------------
__global__ __launch_bounds__(256) void conv_silu_kernel(
    const float* __restrict__ xz, const float* __restrict__ Wc,
    const float* __restrict__ bc, float* __restrict__ xc) {
  int idx = blockIdx.x * blockDim.x + threadIdx.x;   // over M_SZ*DI
  if (idx >= M_SZ * DI) return;
  int d  = idx & (DI - 1);
  int bl = idx >> 11;            // row index (b*L + l), DI = 2^11
  int l  = bl & (L_SZ - 1);
  float4 w = ((const float4*)Wc)[d];  // W_conv[d][0][0..3]
  const float* base = xz + (size_t)bl * N_XZ + d;
  float s = bc[d] + base[0] * w.w;                     // k=3 tap -> current t
  if (l >= 1) s = fmaf(base[-N_XZ],     w.z, s);
  if (l >= 2) s = fmaf(base[-2 * N_XZ], w.y, s);
  if (l >= 3) s = fmaf(base[-3 * N_XZ], w.x, s);
  float sig = 1.f / (1.f + expf(-s));
  xc[idx] = s * sig;
}

// ---------------- skinny GEMM: Bm = xc @ W_B + b_B ; Cm = xc @ W_C + b_C ----------------
__global__ __launch_bounds__(256) void gemm_bc_kernel(
    const float* __restrict__ xc,
    const float* __restrict__ WB, const float* __restrict__ bB,
    const float* __restrict__ WC, const float* __restrict__ bC,
    float* __restrict__ Bm, float* __restrict__ Cm) {
  int t = blockIdx.x * blockDim.x + threadIdx.x;  // M_SZ*32
  int row = t >> 5;
  int cc  = t & 31;
  int s   = cc & 15;
  const float* W = (cc < 16) ? WB : WC;
  const float4* xr4 = (const float4*)(xc + (size_t)row * DI);
  float acc = 0.f;
  #pragma unroll 4
  for (int k4 = 0; k4 < DI / 4; ++k4) {
    float4 xv = xr4[k4];
    int k = k4 * 4;
    acc = fmaf(xv.x, W[(k    ) * DS + s], acc);
    acc = fmaf(xv.y, W[(k + 1) * DS + s], acc);
    acc = fmaf(xv.z, W[(k + 2) * DS + s], acc);
    acc = fmaf(xv.w, W[(k + 3) * DS + s], acc);
  }
  if (cc < 16) Bm[row * DS + s] = acc + bB[s];
  else         Cm[row * DS + s] = acc + bC[s];
}

// ---------------- selective scan (sequential over L), s-parallel ----------------
#define CHUNK 64
#define SROW  20   // padded stage-array stride
__global__ __launch_bounds__(256) void scan_kernel(
    const float* xc, const float* __restrict__ xz,
    const float* __restrict__ Bm, const float* __restrict__ Cm,
    const float* __restrict__ A_log, const float* __restrict__ Dv,
    float* yg) {
  const int b   = blockIdx.y;
  const int d0  = blockIdx.x * 16;
  const int tid = threadIdx.x;
  const int dd  = tid >> 4;    // local channel 0..15
  const int s   = tid & 15;    // state 0..15
  const int d   = d0 + dd;

  __shared__ float Xs[CHUNK * SROW];
  __shared__ float Zs[CHUNK * SROW];
  __shared__ float Bs[CHUNK * SROW];
  __shared__ float Cs[CHUNK * SROW];
  __shared__ float Ps[CHUNK * 256];   // 64 KB: partial products h*C

  float Alog = A_log[d * DS + s];
  Alog = fminf(fmaxf(Alog, -10.f), 2.f);
  const float A  = -expf(Alog);
  const float Dr = Dv[d0 + (tid & 15)];  // channel handled in reduce phase
  float h = 0.f;

  const int sl = tid >> 2;   // 0..63
  const int sc = tid & 3;    // 0..3

  for (int l0 = 0; l0 < L_SZ; l0 += CHUNK) {
    __syncthreads();
    {
      size_t row = (size_t)(b * L_SZ + l0 + sl);
      float4 xv = *(const float4*)(xc + row * DI + d0 + sc * 4);
      float4 zv = *(const float4*)(xz + row * N_XZ + DI + d0 + sc * 4);
      float4 bv = *(const float4*)(Bm + row * DS + sc * 4);
      float4 cv = *(const float4*)(Cm + row * DS + sc * 4);
      *(float4*)(Xs + sl * SROW + sc * 4) = xv;
      *(float4*)(Zs + sl * SROW + sc * 4) = zv;
      *(float4*)(Bs + sl * SROW + sc * 4) = bv;
      *(float4*)(Cs + sl * SROW + sc * 4) = cv;
    }
    __syncthreads();

    #pragma unroll 8
    for (int l = 0; l < CHUNK; ++l) {
      float x  = Xs[l * SROW + dd];
      float Bv = Bs[l * SROW + s];
      float Cv = Cs[l * SROW + s];
      h = fmaf(h, A, x * Bv);
      h = fminf(fmaxf(h, -100.f), 100.f);
      Ps[l * 256 + tid] = h * Cv;
    }
    __syncthreads();

    #pragma unroll
    for (int i = 0; i < 4; ++i) {
      int idx = tid + i * 256;
      int l   = idx >> 4;
      int ddr = idx & 15;
      const float* p = Ps + l * 256 + ddr * 16;
      float v[16];
      #pragma unroll
      for (int j = 0; j < 16; ++j)
        v[j] = p[(j + ddr) & 15];
      float t0 = (v[0] + v[1]) + (v[2] + v[3]);
      float t1 = (v[4] + v[5]) + (v[6] + v[7]);
      float t2 = (v[8] + v[9]) + (v[10] + v[11]);
      float t3 = (v[12] + v[13]) + (v[14] + v[15]);
      float sum = (t0 + t1) + (t2 + t3);
      float xv = Xs[l * SROW + ddr];
      float y  = fmaf(Dr, xv, sum);
      y = fminf(fmaxf(y, -100.f), 100.f);
      float zv = Zs[l * SROW + ddr];
      float g  = 1.f / (1.f + expf(-zv));
      yg[((size_t)(b * L_SZ + l0 + l)) * DI + d0 + ddr] = y * g;
    }
  }
}

// ---------------- launch ----------------
extern "C" void kernel_launch(void* const* d_in, const int* in_sizes, int n_in,
                              void* d_out, int out_size, void* d_ws, size_t ws_size,
                              hipStream_t stream) {
  const float* x      = (const float*)d_in[0];
  const float* W_in   = (const float*)d_in[1];
  const float* b_in   = (const float*)d_in[2];
  const float* W_conv = (const float*)d_in[3];
  const float* b_conv = (const float*)d_in[4];
  const float* A_log  = (const float*)d_in[5];
  const float* Dv     = (const float*)d_in[6];
  const float* W_B    = (const float*)d_in[7];
  const float* b_B    = (const float*)d_in[8];
  const float* W_C    = (const float*)d_in[9];
  const float* b_C    = (const float*)d_in[10];
  const float* W_out  = (const float*)d_in[11];
  const float* b_out  = (const float*)d_in[12];
  float* out = (float*)d_out;

  float* ws = (float*)d_ws;
  float* xz = ws;                       // M_SZ*N_XZ
  float* xc = ws + (size_t)M_SZ * N_XZ; // M_SZ*DI
  float* Bm = xc + (size_t)M_SZ * DI;   // M_SZ*DS
  float* Cm = Bm + (size_t)M_SZ * DS;   // M_SZ*DS
  float* yg = xc;                       // alias: scan stages to LDS before overwrite

  // 1a) xz[:, 0:2048] = x @ W_in[:, 0:2048] + b_in[0:2048]   fp32 (scan-sensitive)
  {
    dim3 grid(DI / 128, M_SZ / 128);   // (16, 32)
    gemm_xi_f32<<<grid, 256, 0, stream>>>(x, W_in, b_in, xz);
  }
  // 1b) xz[:, 2048:4096] = x @ W_in[:, 2048:] + b_in[2048:]  bf16 MFMA (gate path)
  {
    dim3 grid(DI / 128, M_SZ / 128);   // (16, 32)
    gemm_mfma<<<grid, 256, 0, stream>>>(x, DM, W_in + DI, N_XZ,
                                        b_in + DI, xz + DI, N_XZ, DM);
  }
  // 2) xc = silu(causal_dwconv(xi) + b_conv)
  {
    int n = M_SZ * DI;
    conv_silu_kernel<<<n / 256, 256, 0, stream>>>(xz, W_conv, b_conv, xc);
  }
  // 3) Bm, Cm projections (fp32 -> feed the scan)
  {
    int n = M_SZ * 32;
    gemm_bc_kernel<<<n / 256, 256, 0, stream>>>(xc, W_B, b_B, W_C, b_C, Bm, Cm);
  }
  // 4) selective scan + gating (writes yg, aliasing xc)
  {
    dim3 grid(DI / 16, B_SZ);
    scan_kernel<<<grid, 256, 0, stream>>>(xc, xz, Bm, Cm, A_log, Dv, yg);
  }
  // 5) out = yg @ W_out + b_out        (4096 x 1024 x 2048), bf16 MFMA
  {
    dim3 grid(DM / 128, M_SZ / 128);   // (8, 32)
    gemm_mfma<<<grid, 256, 0, stream>>>(yg, DI, W_out, DM, b_out, out, DM, DI);
  }
}

// Round 6
// 818.619 us; speedup vs baseline: 1.0322x; 1.0322x over previous
//
#include <hip/hip_runtime.h>
#include <hip/hip_bf16.h>
#include <math.h>

// ---------------- problem constants ----------------
#define B_SZ   2
#define L_SZ   2048
#define DM     1024          // d_model
#define DI     2048          // d_inner
#define DS     16            // d_state
#define M_SZ   (B_SZ * L_SZ) // 4096 rows
#define N_XZ   (2 * DI)      // 4096
// ws layout (floats):
//   xz : [0,        16777216)   M_SZ*N_XZ
//   xc : [16777216, 25165824)   M_SZ*DI   (conv+silu out; later aliased by y_gated)
//   Bm : [25165824, 25231360)   M_SZ*DS
//   Cm : [25231360, 25296896)   M_SZ*DS

typedef short bf16x8 __attribute__((ext_vector_type(8)));
typedef float f32x4  __attribute__((ext_vector_type(4)));

// pack two fp32 -> two bf16 (RNE) in one dword (a=lo, b=hi)
__device__ __forceinline__ unsigned int pk_bf16(float a, float b) {
  unsigned int ua = __builtin_bit_cast(unsigned int, a);
  unsigned int ub = __builtin_bit_cast(unsigned int, b);
  ua += 0x7FFFu + ((ua >> 16) & 1u);
  ub += 0x7FFFu + ((ub >> 16) & 1u);
  return (ua >> 16) | (ub & 0xFFFF0000u);
}

// ---------------- fp32 GEMM for xi half (feeds the scan -> MUST stay fp32) ----------------
// Round-5 lesson: bf16 xi -> absmax 16 (scan amplifies ~4000x). Do not re-try.
// xz[:, 0:2048] = x @ W_in[:, 0:2048] + b_in[0:2048]
// 128x128 tile, BK=16, 8x8/thread split 4+4 at +64 (conflict-free frag reads).
__global__ __launch_bounds__(256, 2) void gemm_xi_f32(
    const float* __restrict__ A,    // x (M_SZ x DM)
    const float* __restrict__ B,    // W_in (DM x N_XZ), cols 0..2047
    const float* __restrict__ bias, float* __restrict__ C) {  // xz, stride N_XZ
  __shared__ float As[16][132];   // transposed A tile, +4 pad
  __shared__ float Bs[16][128];
  const int tid = threadIdx.x;
  const int tr = tid >> 4;        // 0..15
  const int tc = tid & 15;        // 0..15
  const int row0 = blockIdx.y * 128, col0 = blockIdx.x * 128;

  float acc[8][8] = {};

  for (int k0 = 0; k0 < DM; k0 += 16) {
    __syncthreads();
    #pragma unroll
    for (int i = 0; i < 2; ++i) {
      int idx = tid + i * 256, r = idx >> 2, q = idx & 3;
      float4 v = *(const float4*)(A + (size_t)(row0 + r) * DM + k0 + q * 4);
      As[q * 4 + 0][r] = v.x; As[q * 4 + 1][r] = v.y;
      As[q * 4 + 2][r] = v.z; As[q * 4 + 3][r] = v.w;
    }
    #pragma unroll
    for (int i = 0; i < 2; ++i) {
      int idx = tid + i * 256, kk = idx >> 5, qc = idx & 31;
      *(float4*)&Bs[kk][qc * 4] =
          *(const float4*)(B + (size_t)(k0 + kk) * N_XZ + col0 + qc * 4);
    }
    __syncthreads();
    #pragma unroll
    for (int kk = 0; kk < 16; ++kk) {
      float a[8], b[8];
      *(float4*)&a[0] = *(const float4*)&As[kk][tr * 4];
      *(float4*)&a[4] = *(const float4*)&As[kk][64 + tr * 4];
      *(float4*)&b[0] = *(const float4*)&Bs[kk][tc * 4];
      *(float4*)&b[4] = *(const float4*)&Bs[kk][64 + tc * 4];
      #pragma unroll
      for (int i2 = 0; i2 < 8; ++i2)
        #pragma unroll
        for (int j2 = 0; j2 < 8; ++j2)
          acc[i2][j2] = fmaf(a[i2], b[j2], acc[i2][j2]);
    }
  }
  #pragma unroll
  for (int ii = 0; ii < 2; ++ii)
    #pragma unroll
    for (int i = 0; i < 4; ++i) {
      int r = row0 + ii * 64 + tr * 4 + i;
      #pragma unroll
      for (int jj = 0; jj < 2; ++jj) {
        int c = col0 + jj * 64 + tc * 4;
        float4 o;
        o.x = acc[ii * 4 + i][jj * 4 + 0] + bias[c + 0];
        o.y = acc[ii * 4 + i][jj * 4 + 1] + bias[c + 1];
        o.z = acc[ii * 4 + i][jj * 4 + 2] + bias[c + 2];
        o.w = acc[ii * 4 + i][jj * 4 + 3] + bias[c + 3];
        *(float4*)(C + (size_t)r * N_XZ + c) = o;
      }
    }
}

// ---------------- bf16 MFMA GEMM, generalized strides + L2 supertile swizzle ----------------
// 1-D grid; supertile = 8 row-blocks x all col-blocks, so the full B panel is
// reused across 8 temporally-adjacent row-blocks (B swept M/128/8 = 4x instead
// of 32x -> r4's 135 MB fetch should drop ~2x+).
#define LDF 20   // uints per LDS row (32 bf16 data + 8 pad)
__global__ __launch_bounds__(256, 3) void gemm_mfma(
    const float* __restrict__ A, int lda,
    const float* __restrict__ B, int ldb,
    const float* __restrict__ bias, float* __restrict__ C, int ldc, int K,
    int col_blocks) {
  __shared__ unsigned int As[128 * LDF];  // [row][k] bf16 pairs
  __shared__ unsigned int Bs[128 * LDF];  // [col][k] bf16 pairs (transposed)
  const int tid  = threadIdx.x;
  const int lane = tid & 63, wave = tid >> 6;
  const int wr = wave >> 1, wc = wave & 1;
  const int lm = lane & 15, lq = lane >> 4;
  // supertile swizzle
  const int id = blockIdx.x;
  const int ssz = 8 * col_blocks;
  const int super = id / ssz, within = id % ssz;
  const int rowb = super * 8 + within / col_blocks;
  const int colb = within % col_blocks;
  const int row0 = rowb * 128, col0 = colb * 128;

  f32x4 acc[4][4];
  #pragma unroll
  for (int i = 0; i < 4; ++i)
    #pragma unroll
    for (int j = 0; j < 4; ++j) acc[i][j] = (f32x4){0.f, 0.f, 0.f, 0.f};

  for (int k0 = 0; k0 < K; k0 += 32) {
    __syncthreads();
    // A: 128 rows x 32 k; float4 along k -> bf16x4 (8B) store
    #pragma unroll
    for (int i = 0; i < 4; ++i) {
      int idx = tid + i * 256, r = idx >> 3, q = idx & 7;
      float4 v = *(const float4*)(A + (size_t)(row0 + r) * lda + k0 + q * 4);
      *(uint2*)&As[r * LDF + q * 2] =
          make_uint2(pk_bf16(v.x, v.y), pk_bf16(v.z, v.w));
    }
    // B: 32 k x 128 n -> [n][k]; gather 4 k's per n (coalesced over n)
    #pragma unroll
    for (int i = 0; i < 4; ++i) {
      int idx = tid + i * 256, n = idx & 127, kq = idx >> 7;
      const float* bp = B + (size_t)(k0 + kq * 4) * ldb + col0 + n;
      float b0 = bp[0], b1 = bp[ldb], b2 = bp[2 * ldb], b3 = bp[3 * ldb];
      *(uint2*)&Bs[n * LDF + kq * 2] =
          make_uint2(pk_bf16(b0, b1), pk_bf16(b2, b3));
    }
    __syncthreads();
    bf16x8 af[4], bf[4];
    #pragma unroll
    for (int i = 0; i < 4; ++i)
      af[i] = *(const bf16x8*)&As[(wr * 64 + i * 16 + lm) * LDF + lq * 4];
    #pragma unroll
    for (int j = 0; j < 4; ++j)
      bf[j] = *(const bf16x8*)&Bs[(wc * 64 + j * 16 + lm) * LDF + lq * 4];
    #pragma unroll
    for (int i = 0; i < 4; ++i)
      #pragma unroll
      for (int j = 0; j < 4; ++j)
        acc[i][j] = __builtin_amdgcn_mfma_f32_16x16x32_bf16(af[i], bf[j], acc[i][j], 0, 0, 0);
  }
  // epilogue: C/D layout col=lane&15, row=(lane>>4)*4+reg
  #pragma unroll
  for (int i = 0; i < 4; ++i) {
    int r = row0 + wr * 64 + i * 16 + lq * 4;
    #pragma unroll
    for (int j = 0; j < 4; ++j) {
      int c = col0 + wc * 64 + j * 16 + lm;
      float bs = bias[c];
      #pragma unroll
      for (int k = 0; k < 4; ++k)
        C[(size_t)(r + k) * ldc + c] = acc[i][j][k] + bs;
    }
  }
}

// ---------------- depthwise causal conv (k=4, left pad 3) + SiLU ----------------
__global__ __launch_bounds__(256) void conv_silu_kernel(
    const float* __restrict__ xz, const float* __restrict__ Wc,
    const float* __restrict__ bc, float* __restrict__ xc) {
  int idx = blockIdx.x * blockDim.x + threadIdx.x;   // over M_SZ*DI
  if (idx >= M_SZ * DI) return;
  int d  = idx & (DI - 1);
  int bl = idx >> 11;            // row index (b*L + l), DI = 2^11
  int l  = bl & (L_SZ - 1);
  float4 w = ((const float4*)Wc)[d];  // W_conv[d][0][0..3]
  const float* base = xz + (size_t)bl * N_XZ + d;
  float s = bc[d] + base[0] * w.w;                     // k=3 tap -> current t
  if (l >= 1) s = fmaf(base[-N_XZ],     w.z, s);
  if (l >= 2) s = fmaf(base[-2 * N_XZ], w.y, s);
  if (l >= 3) s = fmaf(base[-3 * N_XZ], w.x, s);
  float sig = 1.f / (1.f + expf(-s));
  xc[idx] = s * sig;
}

// ---------------- skinny GEMM: Bm = xc @ W_B + b_B ; Cm = xc @ W_C + b_C ----------------
__global__ __launch_bounds__(256) void gemm_bc_kernel(
    const float* __restrict__ xc,
    const float* __restrict__ WB, const float* __restrict__ bB,
    const float* __restrict__ WC, const float* __restrict__ bC,
    float* __restrict__ Bm, float* __restrict__ Cm) {
  int t = blockIdx.x * blockDim.x + threadIdx.x;  // M_SZ*32
  int row = t >> 5;
  int cc  = t & 31;
  int s   = cc & 15;
  const float* W = (cc < 16) ? WB : WC;
  const float4* xr4 = (const float4*)(xc + (size_t)row * DI);
  float acc = 0.f;
  #pragma unroll 4
  for (int k4 = 0; k4 < DI / 4; ++k4) {
    float4 xv = xr4[k4];
    int k = k4 * 4;
    acc = fmaf(xv.x, W[(k    ) * DS + s], acc);
    acc = fmaf(xv.y, W[(k + 1) * DS + s], acc);
    acc = fmaf(xv.z, W[(k + 2) * DS + s], acc);
    acc = fmaf(xv.w, W[(k + 3) * DS + s], acc);
  }
  if (cc < 16) Bm[row * DS + s] = acc + bB[s];
  else         Cm[row * DS + s] = acc + bC[s];
}

// ---------------- selective scan: barrier-free single-wave blocks ----------------
// 1024 blocks x 64 thr; block = 4 channels x 16 states (one wave).
// No __syncthreads: all LDS producer/consumer pairs are same-wave (in-order
// LDS pipe). Register prefetch of next chunk overlaps global latency.
#define SCH   4     // channels per block
#define CHUNK 64
#define XSTR  66    // Xs2 [ch][l] padded stride
#define PSTR  68    // Ps  [l][tid] padded stride
__global__ __launch_bounds__(64) void scan_kernel(
    const float* xc, const float* __restrict__ xz,
    const float* __restrict__ Bm, const float* __restrict__ Cm,
    const float* __restrict__ A_log, const float* __restrict__ Dv,
    float* yg) {
  const int b   = blockIdx.y;
  const int d0  = blockIdx.x * SCH;
  const int tid = threadIdx.x;   // 0..63
  const int dd  = tid >> 4;      // 0..3  channel
  const int s   = tid & 15;      // state

  __shared__ float Xs2[SCH * XSTR];     // [ch][l]
  __shared__ float Zs[CHUNK * SCH];     // [l][ch]
  __shared__ float BCs[CHUNK * DS * 2]; // [l][s][{B,C}] interleaved
  __shared__ float Ps[CHUNK * PSTR];    // [l][tid] partial h*C

  float Alog = A_log[(d0 + dd) * DS + s];
  Alog = fminf(fmaxf(Alog, -10.f), 2.f);
  const float A  = -expf(Alog);
  const float Dr = Dv[d0 + (tid & 3)];
  float h = 0.f;

  const size_t rbase = (size_t)b * L_SZ;

  float4 pX, pZ, pB[4], pC[4];
  {
    size_t row = rbase + tid;
    pX = *(const float4*)(xc + row * DI + d0);
    pZ = *(const float4*)(xz + row * N_XZ + DI + d0);
    #pragma unroll
    for (int i = 0; i < 4; ++i) {
      int idx = tid + i * 64;
      size_t rr = rbase + (idx >> 2);
      pB[i] = *(const float4*)(Bm + rr * DS + (idx & 3) * 4);
      pC[i] = *(const float4*)(Cm + rr * DS + (idx & 3) * 4);
    }
  }

  for (int l0 = 0; l0 < L_SZ; l0 += CHUNK) {
    Xs2[0 * XSTR + tid] = pX.x;
    Xs2[1 * XSTR + tid] = pX.y;
    Xs2[2 * XSTR + tid] = pX.z;
    Xs2[3 * XSTR + tid] = pX.w;
    *(float4*)(Zs + tid * 4) = pZ;
    #pragma unroll
    for (int i = 0; i < 4; ++i) {
      int idx = tid + i * 64;
      float* bb = BCs + idx * 8;
      *(float2*)(bb + 0) = make_float2(pB[i].x, pC[i].x);
      *(float2*)(bb + 2) = make_float2(pB[i].y, pC[i].y);
      *(float2*)(bb + 4) = make_float2(pB[i].z, pC[i].z);
      *(float2*)(bb + 6) = make_float2(pB[i].w, pC[i].w);
    }
    if (l0 + CHUNK < L_SZ) {
      size_t row = rbase + l0 + CHUNK + tid;
      pX = *(const float4*)(xc + row * DI + d0);
      pZ = *(const float4*)(xz + row * N_XZ + DI + d0);
      #pragma unroll
      for (int i = 0; i < 4; ++i) {
        int idx = tid + i * 64;
        size_t rr = rbase + l0 + CHUNK + (idx >> 2);
        pB[i] = *(const float4*)(Bm + rr * DS + (idx & 3) * 4);
        pC[i] = *(const float4*)(Cm + rr * DS + (idx & 3) * 4);
      }
    }
    #pragma unroll 8
    for (int l = 0; l < CHUNK; l += 2) {
      float2 x2  = *(const float2*)&Xs2[dd * XSTR + l];
      float2 bc0 = *(const float2*)&BCs[l * 32 + s * 2];
      float2 bc1 = *(const float2*)&BCs[(l + 1) * 32 + s * 2];
      h = fmaf(h, A, x2.x * bc0.x);
      h = fminf(fmaxf(h, -100.f), 100.f);
      float p0 = h * bc0.y;
      h = fmaf(h, A, x2.y * bc1.x);
      h = fminf(fmaxf(h, -100.f), 100.f);
      float p1 = h * bc1.y;
      Ps[l * PSTR + tid]       = p0;
      Ps[(l + 1) * PSTR + tid] = p1;
    }
    #pragma unroll
    for (int i = 0; i < 4; ++i) {
      int idx = tid + i * 64;
      int l   = idx >> 2;
      int ddr = idx & 3;
      const float* pp = Ps + l * PSTR + ddr * 16;
      float4 a0 = *(const float4*)(pp + 0);
      float4 a1 = *(const float4*)(pp + 4);
      float4 a2 = *(const float4*)(pp + 8);
      float4 a3 = *(const float4*)(pp + 12);
      float t0 = (a0.x + a0.y) + (a0.z + a0.w);
      float t1 = (a1.x + a1.y) + (a1.z + a1.w);
      float t2 = (a2.x + a2.y) + (a2.z + a2.w);
      float t3 = (a3.x + a3.y) + (a3.z + a3.w);
      float sum = (t0 + t1) + (t2 + t3);
      float xv = Xs2[ddr * XSTR + l];
      float y  = fmaf(Dr, xv, sum);
      y = fminf(fmaxf(y, -100.f), 100.f);
      float g = 1.f / (1.f + expf(-Zs[l * 4 + ddr]));
      yg[(rbase + l0 + l) * DI + d0 + ddr] = y * g;
    }
  }
}

// ---------------- launch ----------------
extern "C" void kernel_launch(void* const* d_in, const int* in_sizes, int n_in,
                              void* d_out, int out_size, void* d_ws, size_t ws_size,
                              hipStream_t stream) {
  const float* x      = (const float*)d_in[0];
  const float* W_in   = (const float*)d_in[1];
  const float* b_in   = (const float*)d_in[2];
  const float* W_conv = (const float*)d_in[3];
  const float* b_conv = (const float*)d_in[4];
  const float* A_log  = (const float*)d_in[5];
  const float* Dv     = (const float*)d_in[6];
  const float* W_B    = (const float*)d_in[7];
  const float* b_B    = (const float*)d_in[8];
  const float* W_C    = (const float*)d_in[9];
  const float* b_C    = (const float*)d_in[10];
  const float* W_out  = (const float*)d_in[11];
  const float* b_out  = (const float*)d_in[12];
  float* out = (float*)d_out;

  float* ws = (float*)d_ws;
  float* xz = ws;                       // M_SZ*N_XZ
  float* xc = ws + (size_t)M_SZ * N_XZ; // M_SZ*DI
  float* Bm = xc + (size_t)M_SZ * DI;   // M_SZ*DS
  float* Cm = Bm + (size_t)M_SZ * DS;   // M_SZ*DS
  float* yg = xc;                       // alias: disjoint rows/cols per block

  // 1a) xi half: fp32 (scan-sensitive — bf16 here fails, see r5)
  {
    dim3 grid(DI / 128, M_SZ / 128);   // (16, 32)
    gemm_xi_f32<<<grid, 256, 0, stream>>>(x, W_in, b_in, xz);
  }
  // 1b) z half: bf16 MFMA with L2 supertile swizzle (gate path)
  {
    int col_blocks = DI / 128;          // 16
    int nblk = (M_SZ / 128) * col_blocks;
    gemm_mfma<<<nblk, 256, 0, stream>>>(x, DM, W_in + DI, N_XZ,
                                        b_in + DI, xz + DI, N_XZ, DM, col_blocks);
  }
  // 2) xc = silu(causal_dwconv(xi) + b_conv)
  {
    int n = M_SZ * DI;
    conv_silu_kernel<<<n / 256, 256, 0, stream>>>(xz, W_conv, b_conv, xc);
  }
  // 3) Bm, Cm projections (fp32 on conv output)
  {
    int n = M_SZ * 32;
    gemm_bc_kernel<<<n / 256, 256, 0, stream>>>(xc, W_B, b_B, W_C, b_C, Bm, Cm);
  }
  // 4) selective scan + gating (barrier-free, 1024 single-wave blocks)
  {
    dim3 grid(DI / SCH, B_SZ);           // (512, 2)
    scan_kernel<<<grid, 64, 0, stream>>>(xc, xz, Bm, Cm, A_log, Dv, yg);
  }
  // 5) out = yg @ W_out + b_out   (4096 x 1024 x 2048), bf16 MFMA + swizzle
  {
    int col_blocks = DM / 128;          // 8
    int nblk = (M_SZ / 128) * col_blocks;
    gemm_mfma<<<nblk, 256, 0, stream>>>(yg, DI, W_out, DM, b_out, out, DM, DI, col_blocks);
  }
}